// Round 12
// baseline (714.751 us; speedup 1.0000x reference)
//
#include <hip/hip_runtime.h>

#define N_NODES 100000
#define N_EDGES 3200000
#define FEAT 256
#define HID 128
#define OUT 64
#define HOPS 3

#define NPAD 100352                      // 98*1024, >= N_NODES
#define NTOT (2 * NPAD)                  // combined s|t dst-unit space = 200704
#define NBUCK 196                        // NTOT / 1024 buckets (1024 units each)
#define CAP 36864                        // fixed bucket capacity (mean 32768, +22 sigma)
#define RPS 1028                         // rowptr stride per bucket (1024 starts + end slot)
#define EPB 2048                         // edges per block in CSR-build passes

typedef unsigned short ushort_t;

__device__ __forceinline__ float bf2f(ushort_t u) {
    return __uint_as_float(((unsigned)u) << 16);
}
__device__ __forceinline__ float bflo(unsigned u) { return __uint_as_float(u << 16); }
__device__ __forceinline__ float bfhi(unsigned u) { return __uint_as_float(u & 0xffff0000u); }
__device__ __forceinline__ unsigned pack_bf16(float a, float b) {
    unsigned ua = __float_as_uint(a);
    unsigned ub = __float_as_uint(b);
    ua += 0x7fffu + ((ua >> 16) & 1u);
    ub += 0x7fffu + ((ub >> 16) & 1u);
    return (ua >> 16) | (ub & 0xffff0000u);
}

// ---------------- weight fold: Wc = W_{src,tgt} @ Wn_half ; bc = b @ Wn_half
__global__ __launch_bounds__(64) void wcomb_k(
    const float* __restrict__ Wsrc, const float* __restrict__ Wtgt,
    const float* __restrict__ bsrc, const float* __restrict__ btgt,
    const float* __restrict__ Wn,     // [2*HID, OUT]
    float* __restrict__ Wc,           // [512, 64]
    float* __restrict__ bc)           // [128]
{
    const int blk = blockIdx.x;
    const int j = threadIdx.x;
    if (blk < 512) {
        const float* Wsel = (blk < 256) ? Wsrc : Wtgt;
        const int i = blk & 255;
        const int koff = (blk < 256) ? 0 : HID;
        float acc = 0.f;
        for (int k = 0; k < HID; ++k)
            acc = fmaf(Wsel[i * HID + k], Wn[(koff + k) * OUT + j], acc);
        Wc[blk * OUT + j] = acc;
    } else {
        const float* bsel = (blk == 512) ? bsrc : btgt;
        const int koff = (blk == 512) ? 0 : HID;
        float acc = 0.f;
        for (int k = 0; k < HID; ++k)
            acc = fmaf(bsel[k], Wn[(koff + k) * OUT + j], acc);
        bc[(blk - 512) * OUT + j] = acc;
    }
}

// ---------------- input GEMM: h0 = bf16(X @ Wc + bc) ------------------------
__global__ __launch_bounds__(256) void gemm_in(
    const float* __restrict__ X,      // [N, FEAT]
    const float* __restrict__ B,      // [FEAT, OUT] folded weights
    const float* __restrict__ bias,   // [OUT] folded bias
    ushort_t* __restrict__ h0)        // [N, OUT] bf16
{
    __shared__ __align__(16) float at[64][76];   // A transposed [kk][row]
    __shared__ __align__(16) float bs[64][OUT];  // B chunk [kk][j]
    const int tid = threadIdx.x;
    const int tx = tid & 15;          // cols tx*4 .. tx*4+3
    const int ty = tid >> 4;          // rows ty*4 .. ty*4+3
    const int row0 = blockIdx.x * 64;

    float acc[4][4];
#pragma unroll
    for (int r = 0; r < 4; ++r)
#pragma unroll
        for (int c = 0; c < 4; ++c) acc[r][c] = 0.f;

    for (int chunk = 0; chunk < 4; ++chunk) {
        const int kbase = chunk * 64;
        {
            int lc = tid & 15, lr = tid >> 4;
#pragma unroll
            for (int p = 0; p < 4; ++p) {
                int r = lr + p * 16;
                int grow = row0 + r; if (grow > N_NODES - 1) grow = N_NODES - 1;
                float4 v = *(const float4*)(X + (size_t)grow * FEAT + kbase + lc * 4);
                float vv[4] = {v.x, v.y, v.z, v.w};
#pragma unroll
                for (int i = 0; i < 4; ++i) {
                    int ii = (i + lc) & 3;       // rotate to spread banks
                    at[lc * 4 + ii][r] = vv[ii];
                }
            }
        }
        {
            int jf = tid & 15, kk0 = tid >> 4;
#pragma unroll
            for (int p = 0; p < 4; ++p) {
                int kk = kk0 + p * 16;
                *(float4*)&bs[kk][jf * 4] =
                    *(const float4*)(B + (size_t)(kbase + kk) * OUT + jf * 4);
            }
        }
        __syncthreads();
#pragma unroll 8
        for (int kk = 0; kk < 64; ++kk) {
            float4 a = *(const float4*)&at[kk][ty * 4];
            float4 b = *(const float4*)&bs[kk][tx * 4];
            float av[4] = {a.x, a.y, a.z, a.w};
            float bv[4] = {b.x, b.y, b.z, b.w};
#pragma unroll
            for (int r = 0; r < 4; ++r)
#pragma unroll
                for (int c = 0; c < 4; ++c)
                    acc[r][c] = fmaf(av[r], bv[c], acc[r][c]);
        }
        __syncthreads();
    }

    float4 bj = *(const float4*)(bias + tx * 4);
    float bjv[4] = {bj.x, bj.y, bj.z, bj.w};
#pragma unroll
    for (int r = 0; r < 4; ++r) {
        int grow = row0 + ty * 4 + r;
        if (grow < N_NODES) {
            float o[4];
#pragma unroll
            for (int c = 0; c < 4; ++c) o[c] = acc[r][c] + bjv[c];
            size_t off = (size_t)grow * OUT + tx * 4;
            *(uint2*)(h0 + off) = make_uint2(pack_bf16(o[0], o[1]), pack_bf16(o[2], o[3]));
        }
    }
}

// ---------------- init per-bucket allocator cursors -------------------------
__global__ __launch_bounds__(256) void init_k(int* __restrict__ bcur) {
    int t = threadIdx.x;
    if (t < NBUCK) bcur[t] = t * CAP;
}

// ---------------- CSR build pass 1: multisplit scatter into buckets ---------
// entry: .x = src(17b) | dstlow(10b)<<17 ; .y = weight bits
__global__ __launch_bounds__(256) void fill_p1(
    const int* __restrict__ erow, const int* __restrict__ ecol,
    const float* __restrict__ ew,
    int* __restrict__ bcur, int2* __restrict__ meta_tmp)
{
    __shared__ int2 stage[2 * EPB];
    __shared__ unsigned char bkt[2 * EPB];
    __shared__ int lcnt[256], loff[256], gbase[256], cur[256];
    __shared__ int sdata[256];
    const int tid = threadIdx.x;
    const int base = blockIdx.x * EPB;
    const int n = min(EPB, N_EDGES - base);

    int r[8], c[8], wb[8];
    lcnt[tid] = 0;
    __syncthreads();
#pragma unroll
    for (int k = 0; k < 8; ++k) {
        int i = k * 256 + tid;
        if (i < n) {
            int e = base + i;
            r[k] = erow[e];
            c[k] = ecol[e];
            wb[k] = __float_as_int(ew[e]);
            atomicAdd(&lcnt[r[k] >> 10], 1);
            atomicAdd(&lcnt[(NPAD + c[k]) >> 10], 1);
        } else {
            r[k] = -1;
        }
    }
    __syncthreads();
    sdata[tid] = lcnt[tid];
    __syncthreads();
    for (int off = 1; off < 256; off <<= 1) {
        int t = (tid >= off) ? sdata[tid - off] : 0;
        __syncthreads();
        sdata[tid] += t;
        __syncthreads();
    }
    loff[tid] = sdata[tid] - lcnt[tid];
    cur[tid] = loff[tid];
    gbase[tid] = (lcnt[tid] > 0) ? atomicAdd(&bcur[tid], lcnt[tid]) : 0;
    __syncthreads();
#pragma unroll
    for (int k = 0; k < 8; ++k) {
        if (r[k] >= 0) {
            int bs_ = r[k] >> 10;
            int l = atomicAdd(&cur[bs_], 1);
            stage[l] = make_int2(c[k] | ((r[k] & 1023) << 17), wb[k]);
            bkt[l] = (unsigned char)bs_;
            int ut = NPAD + c[k];
            int bt_ = ut >> 10;
            int l2 = atomicAdd(&cur[bt_], 1);
            stage[l2] = make_int2(r[k] | ((ut & 1023) << 17), wb[k]);
            bkt[l2] = (unsigned char)bt_;
        }
    }
    __syncthreads();
    const int tot = 2 * n;
    for (int i = tid; i < tot; i += 256) {
        int b = bkt[i];
        meta_tmp[(size_t)gbase[b] + (i - loff[b])] = stage[i];
    }
}

// ---------------- CSR build pass 2: within-bucket sort + rowptr -------------
// sort key = (dstlow, src>>15): edges within a row are grouped by 4MB
// src-chunk so spmm gathers sweep one L2-sized window at a time.
// final meta entry: .x = src row BYTE offset (src*128), .y = weight bits
__global__ __launch_bounds__(256) void fill_p2(
    const int* __restrict__ bcur,
    const int2* __restrict__ meta_tmp,
    int2* __restrict__ meta, int* __restrict__ rowptr)
{
    __shared__ int cnt[4096];            // 1024 rows x 4 src-chunks
    __shared__ int sdata[256];
    const int tid = threadIdx.x;
    const int b = blockIdx.x;
    const int seg0 = b * CAP;
    const int seg1 = bcur[b];

    for (int i = tid; i < 4096; i += 256) cnt[i] = 0;
    __syncthreads();
    for (int j = seg0 + tid; j < seg1; j += 256) {
        int2 e = meta_tmp[j];
        int bin = (((e.x >> 17) & 1023) << 2) | ((e.x >> 15) & 3);
        atomicAdd(&cnt[bin], 1);
    }
    __syncthreads();
    // scan 4096 bins: 16 consecutive per thread
    int vals[16];
    int tsum = 0;
#pragma unroll
    for (int k = 0; k < 16; ++k) { vals[k] = cnt[tid * 16 + k]; tsum += vals[k]; }
    sdata[tid] = tsum;
    __syncthreads();
    for (int off = 1; off < 256; off <<= 1) {
        int t = (tid >= off) ? sdata[tid - off] : 0;
        __syncthreads();
        sdata[tid] += t;
        __syncthreads();
    }
    int run = seg0 + sdata[tid] - tsum;
    int rp[4];
#pragma unroll
    for (int k = 0; k < 16; ++k) {
        if ((k & 3) == 0) rp[k >> 2] = run;   // row start = its chunk-0 bin
        int c = vals[k];
        cnt[tid * 16 + k] = run;              // absolute cursor
        run += c;
    }
    *(int4*)(rowptr + b * RPS + tid * 4) = make_int4(rp[0], rp[1], rp[2], rp[3]);
    if (tid == 0) rowptr[b * RPS + 1024] = seg1; // bucket end slot
    __syncthreads();
    for (int j = seg0 + tid; j < seg1; j += 256) {
        int2 e = meta_tmp[j];
        int bin = (((e.x >> 17) & 1023) << 2) | ((e.x >> 15) & 3);
        int pos = atomicAdd(&cnt[bin], 1);
        meta[pos] = make_int2((e.x & 0x1ffff) << 7, e.y);   // byte offset of src row
    }
}

// ---------------- shared row-gather core (quarter-wave, 16-edge iters) ------
__device__ __forceinline__ void row_gather(
    const int* __restrict__ rowptr, const int2* __restrict__ meta,
    const char* __restrict__ xb, int unit, int q, int coffb,
    float& a0, float& a1, float& a2, float& a3)
{
    const int rbase = (unit >> 10) * RPS + (unit & 1023);
    const int start = rowptr[rbase];
    const int end   = rowptr[rbase + 1];

    a0 = 0.f; a1 = 0.f; a2 = 0.f; a3 = 0.f;

    int jb = start;
    int2 m0, m1, m2, m3;
    bool have = (jb + 15 < end);
    if (have) {
        m0 = meta[jb + q];
        m1 = meta[jb + 4 + q];
        m2 = meta[jb + 8 + q];
        m3 = meta[jb + 12 + q];
    }
    while (have) {
        uint2 u0 = *(const uint2*)(xb + (unsigned)m0.x + coffb);
        uint2 u1 = *(const uint2*)(xb + (unsigned)m1.x + coffb);
        uint2 u2 = *(const uint2*)(xb + (unsigned)m2.x + coffb);
        uint2 u3 = *(const uint2*)(xb + (unsigned)m3.x + coffb);
        float w0 = __int_as_float(m0.y), w1 = __int_as_float(m1.y);
        float w2 = __int_as_float(m2.y), w3 = __int_as_float(m3.y);

        const int jn = jb + 16;
        have = (jn + 15 < end);
        if (have) {
            m0 = meta[jn + q];
            m1 = meta[jn + 4 + q];
            m2 = meta[jn + 8 + q];
            m3 = meta[jn + 12 + q];
        }
        jb = jn;

        a0 = fmaf(w0, bflo(u0.x), a0);
        a1 = fmaf(w0, bfhi(u0.x), a1);
        a2 = fmaf(w0, bflo(u0.y), a2);
        a3 = fmaf(w0, bfhi(u0.y), a3);
        a0 = fmaf(w1, bflo(u1.x), a0);
        a1 = fmaf(w1, bfhi(u1.x), a1);
        a2 = fmaf(w1, bflo(u1.y), a2);
        a3 = fmaf(w1, bfhi(u1.y), a3);
        a0 = fmaf(w2, bflo(u2.x), a0);
        a1 = fmaf(w2, bfhi(u2.x), a1);
        a2 = fmaf(w2, bflo(u2.y), a2);
        a3 = fmaf(w2, bfhi(u2.y), a3);
        a0 = fmaf(w3, bflo(u3.x), a0);
        a1 = fmaf(w3, bfhi(u3.x), a1);
        a2 = fmaf(w3, bflo(u3.y), a2);
        a3 = fmaf(w3, bfhi(u3.y), a3);
    }

    if (jb < end) {                      // single masked 16-slot tail
        int jj0 = jb + q,      jj1 = jb + 4 + q;
        int jj2 = jb + 8 + q,  jj3 = jb + 12 + q;
        bool v0 = jj0 < end, v1 = jj1 < end, v2 = jj2 < end, v3 = jj3 < end;
        int2 t0 = meta[v0 ? jj0 : start];
        int2 t1 = meta[v1 ? jj1 : start];
        int2 t2 = meta[v2 ? jj2 : start];
        int2 t3 = meta[v3 ? jj3 : start];
        uint2 u0 = *(const uint2*)(xb + (unsigned)t0.x + coffb);
        uint2 u1 = *(const uint2*)(xb + (unsigned)t1.x + coffb);
        uint2 u2 = *(const uint2*)(xb + (unsigned)t2.x + coffb);
        uint2 u3 = *(const uint2*)(xb + (unsigned)t3.x + coffb);
        float w0 = v0 ? __int_as_float(t0.y) : 0.f;
        float w1 = v1 ? __int_as_float(t1.y) : 0.f;
        float w2 = v2 ? __int_as_float(t2.y) : 0.f;
        float w3 = v3 ? __int_as_float(t3.y) : 0.f;
        a0 = fmaf(w0, bflo(u0.x), a0);
        a1 = fmaf(w0, bfhi(u0.x), a1);
        a2 = fmaf(w0, bflo(u0.y), a2);
        a3 = fmaf(w0, bfhi(u0.y), a3);
        a0 = fmaf(w1, bflo(u1.x), a0);
        a1 = fmaf(w1, bfhi(u1.x), a1);
        a2 = fmaf(w1, bflo(u1.y), a2);
        a3 = fmaf(w1, bfhi(u1.y), a3);
        a0 = fmaf(w2, bflo(u2.x), a0);
        a1 = fmaf(w2, bfhi(u2.x), a1);
        a2 = fmaf(w2, bflo(u2.y), a2);
        a3 = fmaf(w2, bfhi(u2.y), a3);
        a0 = fmaf(w3, bflo(u3.x), a0);
        a1 = fmaf(w3, bfhi(u3.x), a1);
        a2 = fmaf(w3, bflo(u3.y), a2);
        a3 = fmaf(w3, bfhi(u3.y), a3);
    }
}

// ---------------- pure SPMM for hops 1..HOPS-1 ------------------------------
__global__ __launch_bounds__(256) void spmm_k(
    const int* __restrict__ rowptr,
    const int2* __restrict__ meta,
    const ushort_t* __restrict__ xs, const ushort_t* __restrict__ xt,
    ushort_t* __restrict__ ns, ushort_t* __restrict__ nt)
{
    const int unit = blockIdx.x * 4 + (threadIdx.x >> 6);   // one wave per unit
    const int lane = threadIdx.x & 63;
    const int q  = lane >> 4;
    const int sl = lane & 15;

    const ushort_t* x; ushort_t* nxt;
    int node;
    if (unit < NPAD) {
        node = unit;
        if (node >= N_NODES) return;
        x = xs; nxt = ns;
    } else {
        node = unit - NPAD;
        if (node >= N_NODES) return;
        x = xt; nxt = nt;
    }

    float a0, a1, a2, a3;
    row_gather(rowptr, meta, (const char*)x, unit, q, sl * 8, a0, a1, a2, a3);

    a0 += __shfl_xor(a0, 16, 64);
    a1 += __shfl_xor(a1, 16, 64);
    a2 += __shfl_xor(a2, 16, 64);
    a3 += __shfl_xor(a3, 16, 64);
    a0 += __shfl_xor(a0, 32, 64);
    a1 += __shfl_xor(a1, 32, 64);
    a2 += __shfl_xor(a2, 32, 64);
    a3 += __shfl_xor(a3, 32, 64);

    if (q == 0) {
        *(uint2*)(nxt + ((size_t)node << 6) + sl * 4) =
            make_uint2(pack_bf16(a0, a1), pack_bf16(a2, a3));
    }
}

// ---------------- fused last hop + combine -----------------------------------
// one wave per NODE: computes hop-3 for BOTH directions in registers, then
// out = bn + sum_h ws[h]*hs_h + sum_h wt[h]*ht_h  (hop-3 terms in f32).
__global__ __launch_bounds__(256) void spmm_last(
    const int* __restrict__ rowptr,
    const int2* __restrict__ meta,
    const ushort_t* __restrict__ xs, const ushort_t* __restrict__ xt,   // hop-2
    const ushort_t* __restrict__ s0, const ushort_t* __restrict__ s1,   // hop-0/1
    const ushort_t* __restrict__ t0, const ushort_t* __restrict__ t1,
    const float* __restrict__ wsv, const float* __restrict__ wtv,
    const float* __restrict__ bn,
    float* __restrict__ out)
{
    const int node = blockIdx.x * 4 + (threadIdx.x >> 6);
    const int lane = threadIdx.x & 63;
    const int q  = lane >> 4;
    const int sl = lane & 15;
    if (node >= N_NODES) return;
    const int coffb = sl * 8;

    float a0, a1, a2, a3, b0, b1, b2, b3;
    row_gather(rowptr, meta, (const char*)xs, node, q, coffb, a0, a1, a2, a3);
    row_gather(rowptr, meta, (const char*)xt, NPAD + node, q, coffb, b0, b1, b2, b3);

    a0 += __shfl_xor(a0, 16, 64);  b0 += __shfl_xor(b0, 16, 64);
    a1 += __shfl_xor(a1, 16, 64);  b1 += __shfl_xor(b1, 16, 64);
    a2 += __shfl_xor(a2, 16, 64);  b2 += __shfl_xor(b2, 16, 64);
    a3 += __shfl_xor(a3, 16, 64);  b3 += __shfl_xor(b3, 16, 64);
    a0 += __shfl_xor(a0, 32, 64);  b0 += __shfl_xor(b0, 32, 64);
    a1 += __shfl_xor(a1, 32, 64);  b1 += __shfl_xor(b1, 32, 64);
    a2 += __shfl_xor(a2, 32, 64);  b2 += __shfl_xor(b2, 32, 64);
    a3 += __shfl_xor(a3, 32, 64);  b3 += __shfl_xor(b3, 32, 64);

    if (q == 0) {
        const size_t ho = ((size_t)node << 6) + sl * 4;    // bf16 elem offset
        uint2 us0 = *(const uint2*)(s0 + ho);
        uint2 us1 = *(const uint2*)(s1 + ho);
        uint2 us2 = *(const uint2*)(xs + ho);
        uint2 ut0 = *(const uint2*)(t0 + ho);
        uint2 ut1 = *(const uint2*)(t1 + ho);
        uint2 ut2 = *(const uint2*)(xt + ho);
        float ws0 = wsv[0], ws1 = wsv[1], ws2 = wsv[2], ws3 = wsv[3];
        float wt0 = wtv[0], wt1 = wtv[1], wt2 = wtv[2], wt3 = wtv[3];
        float4 bb = *(const float4*)(bn + sl * 4);

        float o0 = bb.x + ws0 * bflo(us0.x) + ws1 * bflo(us1.x) + ws2 * bflo(us2.x)
                 + ws3 * a0 + wt0 * bflo(ut0.x) + wt1 * bflo(ut1.x) + wt2 * bflo(ut2.x)
                 + wt3 * b0;
        float o1 = bb.y + ws0 * bfhi(us0.x) + ws1 * bfhi(us1.x) + ws2 * bfhi(us2.x)
                 + ws3 * a1 + wt0 * bfhi(ut0.x) + wt1 * bfhi(ut1.x) + wt2 * bfhi(ut2.x)
                 + wt3 * b1;
        float o2 = bb.z + ws0 * bflo(us0.y) + ws1 * bflo(us1.y) + ws2 * bflo(us2.y)
                 + ws3 * a2 + wt0 * bflo(ut0.y) + wt1 * bflo(ut1.y) + wt2 * bflo(ut2.y)
                 + wt3 * b2;
        float o3 = bb.w + ws0 * bfhi(us0.y) + ws1 * bfhi(us1.y) + ws2 * bfhi(us2.y)
                 + ws3 * a3 + wt0 * bfhi(ut0.y) + wt1 * bfhi(ut1.y) + wt2 * bfhi(ut2.y)
                 + wt3 * b3;

        *(float4*)(out + (size_t)node * OUT + sl * 4) = make_float4(o0, o1, o2, o3);
    }
}

extern "C" void kernel_launch(void* const* d_in, const int* in_sizes, int n_in,
                              void* d_out, int out_size, void* d_ws, size_t ws_size,
                              hipStream_t stream) {
    const float* fsrc = (const float*)d_in[0];
    const float* ftgt = (const float*)d_in[1];
    const int*   erow = (const int*)d_in[2];
    const int*   ecol = (const int*)d_in[3];
    const float* ew   = (const float*)d_in[4];
    const float* Wsrc = (const float*)d_in[5];
    const float* bsrc = (const float*)d_in[6];
    const float* Wtgt = (const float*)d_in[7];
    const float* btgt = (const float*)d_in[8];
    const float* ws   = (const float*)d_in[9];
    const float* wt   = (const float*)d_in[10];
    const float* Wn   = (const float*)d_in[11];
    const float* bn   = (const float*)d_in[12];
    float* out = (float*)d_out;

    const size_t buf = (size_t)N_NODES * OUT;   // elements per hop buffer (64-dim)
    char* p = (char*)d_ws;
    ushort_t* hs[3]; ushort_t* ht[3];
    for (int h = 0; h < 3; ++h) {
        hs[h] = (ushort_t*)p; p += buf * 2;
        ht[h] = (ushort_t*)p; p += buf * 2;
    }
    int2* meta     = (int2*)p;  p += (size_t)NBUCK * CAP * 8;   // sparse layout!
    int2* meta_tmp = (int2*)p;  p += (size_t)NBUCK * CAP * 8;
    int* rowptr    = (int*)p;   p += (size_t)NBUCK * RPS * 4 + 64;
    float* Wc      = (float*)p; p += 512 * OUT * 4;
    float* bc      = (float*)p; p += 128 * 4;
    int* bcur      = (int*)p;   p += 256 * 4;

    const int eblocks = (N_EDGES + EPB - 1) / EPB;   // 1563
    const int gblocks = (N_NODES + 63) / 64;         // 1563

    // fold output projection into input weights
    wcomb_k<<<514, 64, 0, stream>>>(Wsrc, Wtgt, bsrc, btgt, Wn, Wc, bc);

    // input GEMMs -> bf16 hop-0 buffers (already projected to 64 dims)
    gemm_in<<<gblocks, 256, 0, stream>>>(fsrc, Wc, bc, hs[0]);
    gemm_in<<<gblocks, 256, 0, stream>>>(ftgt, Wc + 256 * OUT, bc + OUT, ht[0]);

    // CSR build: fixed-capacity buckets, chunk-sorted rows
    init_k<<<1, 256, 0, stream>>>(bcur);
    fill_p1<<<eblocks, 256, 0, stream>>>(erow, ecol, ew, bcur, meta_tmp);
    fill_p2<<<NBUCK, 256, 0, stream>>>(bcur, meta_tmp, meta, rowptr);

    // hops 1..2: both directions per launch
    spmm_k<<<NTOT / 4, 256, 0, stream>>>(rowptr, meta,
                                         hs[0], ht[0], hs[1], ht[1]);
    spmm_k<<<NTOT / 4, 256, 0, stream>>>(rowptr, meta,
                                         hs[1], ht[1], hs[2], ht[2]);

    // hop 3 fused with the weighted combine + bias
    spmm_last<<<NPAD / 4, 256, 0, stream>>>(rowptr, meta,
                                            hs[2], ht[2], hs[0], hs[1],
                                            ht[0], ht[1], ws, wt, bn, out);
}

// Round 13
// 689.607 us; speedup vs baseline: 1.0365x; 1.0365x over previous
//
#include <hip/hip_runtime.h>

#define N_NODES 100000
#define N_EDGES 3200000
#define FEAT 256
#define HID 128
#define OUT 64
#define HOPS 3

#define NPAD 100352                      // 98*1024, >= N_NODES
#define NTOT (2 * NPAD)                  // combined s|t dst-unit space = 200704
#define NBUCK 196                        // NTOT / 1024 buckets (1024 units each)
#define CAP 36864                        // fixed bucket capacity (mean 32768, +22 sigma)
#define RPS 1028                         // rowptr stride per bucket (1024 starts + end slot)
#define EPB 2048                         // edges per block in CSR-build passes

typedef unsigned short ushort_t;

__device__ __forceinline__ float bf2f(ushort_t u) {
    return __uint_as_float(((unsigned)u) << 16);
}
__device__ __forceinline__ float bflo(unsigned u) { return __uint_as_float(u << 16); }
__device__ __forceinline__ float bfhi(unsigned u) { return __uint_as_float(u & 0xffff0000u); }
__device__ __forceinline__ unsigned pack_bf16(float a, float b) {
    unsigned ua = __float_as_uint(a);
    unsigned ub = __float_as_uint(b);
    ua += 0x7fffu + ((ua >> 16) & 1u);
    ub += 0x7fffu + ((ub >> 16) & 1u);
    return (ua >> 16) | (ub & 0xffff0000u);
}

// ---------------- weight fold: Wc = W_{src,tgt} @ Wn_half ; bc = b @ Wn_half
__global__ __launch_bounds__(64) void wcomb_k(
    const float* __restrict__ Wsrc, const float* __restrict__ Wtgt,
    const float* __restrict__ bsrc, const float* __restrict__ btgt,
    const float* __restrict__ Wn,     // [2*HID, OUT]
    float* __restrict__ Wc,           // [512, 64]
    float* __restrict__ bc)           // [128]
{
    const int blk = blockIdx.x;
    const int j = threadIdx.x;
    if (blk < 512) {
        const float* Wsel = (blk < 256) ? Wsrc : Wtgt;
        const int i = blk & 255;
        const int koff = (blk < 256) ? 0 : HID;
        float acc = 0.f;
        for (int k = 0; k < HID; ++k)
            acc = fmaf(Wsel[i * HID + k], Wn[(koff + k) * OUT + j], acc);
        Wc[blk * OUT + j] = acc;
    } else {
        const float* bsel = (blk == 512) ? bsrc : btgt;
        const int koff = (blk == 512) ? 0 : HID;
        float acc = 0.f;
        for (int k = 0; k < HID; ++k)
            acc = fmaf(bsel[k], Wn[(koff + k) * OUT + j], acc);
        bc[(blk - 512) * OUT + j] = acc;
    }
}

// ---------------- input GEMM (both directions in one launch) ----------------
// h = bf16(X @ Wc + bc); blocks [0,gblocks): source dir, [gblocks,2*gblocks): target
__global__ __launch_bounds__(256) void gemm_in(
    const float* __restrict__ Xs, const float* __restrict__ Xt,   // [N, FEAT]
    const float* __restrict__ Wc,    // [512, 64] folded weights (s rows 0-255, t 256-511)
    const float* __restrict__ bc,    // [128] folded biases (s 0-63, t 64-127)
    ushort_t* __restrict__ hs0, ushort_t* __restrict__ ht0,       // [N, OUT] bf16
    int gblocks)
{
    const int dir = (blockIdx.x >= gblocks) ? 1 : 0;
    const int blk = blockIdx.x - dir * gblocks;
    const float* X = dir ? Xt : Xs;
    const float* B = Wc + dir * 256 * OUT;
    const float* bias = bc + dir * OUT;
    ushort_t* h0 = dir ? ht0 : hs0;

    __shared__ __align__(16) float at[64][76];   // A transposed [kk][row]
    __shared__ __align__(16) float bs[64][OUT];  // B chunk [kk][j]
    const int tid = threadIdx.x;
    const int tx = tid & 15;          // cols tx*4 .. tx*4+3
    const int ty = tid >> 4;          // rows ty*4 .. ty*4+3
    const int row0 = blk * 64;

    float acc[4][4];
#pragma unroll
    for (int r = 0; r < 4; ++r)
#pragma unroll
        for (int c = 0; c < 4; ++c) acc[r][c] = 0.f;

    for (int chunk = 0; chunk < 4; ++chunk) {
        const int kbase = chunk * 64;
        {
            int lc = tid & 15, lr = tid >> 4;
#pragma unroll
            for (int p = 0; p < 4; ++p) {
                int r = lr + p * 16;
                int grow = row0 + r; if (grow > N_NODES - 1) grow = N_NODES - 1;
                float4 v = *(const float4*)(X + (size_t)grow * FEAT + kbase + lc * 4);
                float vv[4] = {v.x, v.y, v.z, v.w};
#pragma unroll
                for (int i = 0; i < 4; ++i) {
                    int ii = (i + lc) & 3;       // rotate to spread banks
                    at[lc * 4 + ii][r] = vv[ii];
                }
            }
        }
        {
            int jf = tid & 15, kk0 = tid >> 4;
#pragma unroll
            for (int p = 0; p < 4; ++p) {
                int kk = kk0 + p * 16;
                *(float4*)&bs[kk][jf * 4] =
                    *(const float4*)(B + (size_t)(kbase + kk) * OUT + jf * 4);
            }
        }
        __syncthreads();
#pragma unroll 8
        for (int kk = 0; kk < 64; ++kk) {
            float4 a = *(const float4*)&at[kk][ty * 4];
            float4 b = *(const float4*)&bs[kk][tx * 4];
            float av[4] = {a.x, a.y, a.z, a.w};
            float bv[4] = {b.x, b.y, b.z, b.w};
#pragma unroll
            for (int r = 0; r < 4; ++r)
#pragma unroll
                for (int c = 0; c < 4; ++c)
                    acc[r][c] = fmaf(av[r], bv[c], acc[r][c]);
        }
        __syncthreads();
    }

    float4 bj = *(const float4*)(bias + tx * 4);
    float bjv[4] = {bj.x, bj.y, bj.z, bj.w};
#pragma unroll
    for (int r = 0; r < 4; ++r) {
        int grow = row0 + ty * 4 + r;
        if (grow < N_NODES) {
            float o[4];
#pragma unroll
            for (int c = 0; c < 4; ++c) o[c] = acc[r][c] + bjv[c];
            size_t off = (size_t)grow * OUT + tx * 4;
            *(uint2*)(h0 + off) = make_uint2(pack_bf16(o[0], o[1]), pack_bf16(o[2], o[3]));
        }
    }
}

// ---------------- init per-bucket allocator cursors -------------------------
__global__ __launch_bounds__(256) void init_k(int* __restrict__ bcur) {
    int t = threadIdx.x;
    if (t < NBUCK) bcur[t] = t * CAP;
}

// ---------------- CSR build pass 1: multisplit scatter into buckets ---------
// entry: .x = src(17b) | dstlow(10b)<<17 ; .y = weight bits
__global__ __launch_bounds__(256) void fill_p1(
    const int* __restrict__ erow, const int* __restrict__ ecol,
    const float* __restrict__ ew,
    int* __restrict__ bcur, int2* __restrict__ meta_tmp)
{
    __shared__ int2 stage[2 * EPB];
    __shared__ unsigned char bkt[2 * EPB];
    __shared__ int lcnt[256], loff[256], gbase[256], cur[256];
    __shared__ int sdata[256];
    const int tid = threadIdx.x;
    const int base = blockIdx.x * EPB;
    const int n = min(EPB, N_EDGES - base);

    int r[8], c[8], wb[8];
    lcnt[tid] = 0;
    __syncthreads();
#pragma unroll
    for (int k = 0; k < 8; ++k) {
        int i = k * 256 + tid;
        if (i < n) {
            int e = base + i;
            r[k] = erow[e];
            c[k] = ecol[e];
            wb[k] = __float_as_int(ew[e]);
            atomicAdd(&lcnt[r[k] >> 10], 1);
            atomicAdd(&lcnt[(NPAD + c[k]) >> 10], 1);
        } else {
            r[k] = -1;
        }
    }
    __syncthreads();
    sdata[tid] = lcnt[tid];
    __syncthreads();
    for (int off = 1; off < 256; off <<= 1) {
        int t = (tid >= off) ? sdata[tid - off] : 0;
        __syncthreads();
        sdata[tid] += t;
        __syncthreads();
    }
    loff[tid] = sdata[tid] - lcnt[tid];
    cur[tid] = loff[tid];
    gbase[tid] = (lcnt[tid] > 0) ? atomicAdd(&bcur[tid], lcnt[tid]) : 0;
    __syncthreads();
#pragma unroll
    for (int k = 0; k < 8; ++k) {
        if (r[k] >= 0) {
            int bs_ = r[k] >> 10;
            int l = atomicAdd(&cur[bs_], 1);
            stage[l] = make_int2(c[k] | ((r[k] & 1023) << 17), wb[k]);
            bkt[l] = (unsigned char)bs_;
            int ut = NPAD + c[k];
            int bt_ = ut >> 10;
            int l2 = atomicAdd(&cur[bt_], 1);
            stage[l2] = make_int2(r[k] | ((ut & 1023) << 17), wb[k]);
            bkt[l2] = (unsigned char)bt_;
        }
    }
    __syncthreads();
    const int tot = 2 * n;
    for (int i = tid; i < tot; i += 256) {
        int b = bkt[i];
        meta_tmp[(size_t)gbase[b] + (i - loff[b])] = stage[i];
    }
}

// ---------------- CSR build pass 2: within-bucket sort + rowptr -------------
// (round-11 1024-bin version — chunk-sort was measured neutral-to-negative)
// final meta entry: .x = src row BYTE offset (src*128), .y = weight bits
__global__ __launch_bounds__(256) void fill_p2(
    const int* __restrict__ bcur,
    const int2* __restrict__ meta_tmp,
    int2* __restrict__ meta, int* __restrict__ rowptr)
{
    __shared__ int cnt[1024];
    __shared__ int sdata[256];
    const int tid = threadIdx.x;
    const int b = blockIdx.x;
    const int seg0 = b * CAP;
    const int seg1 = bcur[b];

    for (int i = tid; i < 1024; i += 256) cnt[i] = 0;
    __syncthreads();
    for (int j = seg0 + tid; j < seg1; j += 256) {
        int2 e = meta_tmp[j];
        atomicAdd(&cnt[(e.x >> 17) & 1023], 1);
    }
    __syncthreads();
    int4 v = *(int4*)&cnt[tid * 4];
    int tsum = v.x + v.y + v.z + v.w;
    sdata[tid] = tsum;
    __syncthreads();
    for (int off = 1; off < 256; off <<= 1) {
        int t = (tid >= off) ? sdata[tid - off] : 0;
        __syncthreads();
        sdata[tid] += t;
        __syncthreads();
    }
    int excl = sdata[tid] - tsum;
    int4 o;
    o.x = seg0 + excl;
    o.y = o.x + v.x;
    o.z = o.y + v.y;
    o.w = o.z + v.z;
    *(int4*)(rowptr + b * RPS + tid * 4) = o;    // row starts (absolute into meta)
    *(int4*)&cnt[tid * 4] = o;                   // cursors
    if (tid == 0) rowptr[b * RPS + 1024] = seg1; // bucket end slot
    __syncthreads();
    for (int j = seg0 + tid; j < seg1; j += 256) {
        int2 e = meta_tmp[j];
        int pos = atomicAdd(&cnt[(e.x >> 17) & 1023], 1);
        meta[pos] = make_int2((e.x & 0x1ffff) << 7, e.y);   // byte offset of src row
    }
}

// ---------------- shared row-gather core (quarter-wave, 16-edge iters) ------
__device__ __forceinline__ void row_gather(
    const int* __restrict__ rowptr, const int2* __restrict__ meta,
    const char* __restrict__ xb, int unit, int q, int coffb,
    float& a0, float& a1, float& a2, float& a3)
{
    const int rbase = (unit >> 10) * RPS + (unit & 1023);
    const int start = rowptr[rbase];
    const int end   = rowptr[rbase + 1];

    a0 = 0.f; a1 = 0.f; a2 = 0.f; a3 = 0.f;

    int jb = start;
    int2 m0, m1, m2, m3;
    bool have = (jb + 15 < end);
    if (have) {
        m0 = meta[jb + q];
        m1 = meta[jb + 4 + q];
        m2 = meta[jb + 8 + q];
        m3 = meta[jb + 12 + q];
    }
    while (have) {
        uint2 u0 = *(const uint2*)(xb + (unsigned)m0.x + coffb);
        uint2 u1 = *(const uint2*)(xb + (unsigned)m1.x + coffb);
        uint2 u2 = *(const uint2*)(xb + (unsigned)m2.x + coffb);
        uint2 u3 = *(const uint2*)(xb + (unsigned)m3.x + coffb);
        float w0 = __int_as_float(m0.y), w1 = __int_as_float(m1.y);
        float w2 = __int_as_float(m2.y), w3 = __int_as_float(m3.y);

        const int jn = jb + 16;
        have = (jn + 15 < end);
        if (have) {
            m0 = meta[jn + q];
            m1 = meta[jn + 4 + q];
            m2 = meta[jn + 8 + q];
            m3 = meta[jn + 12 + q];
        }
        jb = jn;

        a0 = fmaf(w0, bflo(u0.x), a0);
        a1 = fmaf(w0, bfhi(u0.x), a1);
        a2 = fmaf(w0, bflo(u0.y), a2);
        a3 = fmaf(w0, bfhi(u0.y), a3);
        a0 = fmaf(w1, bflo(u1.x), a0);
        a1 = fmaf(w1, bfhi(u1.x), a1);
        a2 = fmaf(w1, bflo(u1.y), a2);
        a3 = fmaf(w1, bfhi(u1.y), a3);
        a0 = fmaf(w2, bflo(u2.x), a0);
        a1 = fmaf(w2, bfhi(u2.x), a1);
        a2 = fmaf(w2, bflo(u2.y), a2);
        a3 = fmaf(w2, bfhi(u2.y), a3);
        a0 = fmaf(w3, bflo(u3.x), a0);
        a1 = fmaf(w3, bfhi(u3.x), a1);
        a2 = fmaf(w3, bflo(u3.y), a2);
        a3 = fmaf(w3, bfhi(u3.y), a3);
    }

    if (jb < end) {                      // single masked 16-slot tail
        int jj0 = jb + q,      jj1 = jb + 4 + q;
        int jj2 = jb + 8 + q,  jj3 = jb + 12 + q;
        bool v0 = jj0 < end, v1 = jj1 < end, v2 = jj2 < end, v3 = jj3 < end;
        int2 t0 = meta[v0 ? jj0 : start];
        int2 t1 = meta[v1 ? jj1 : start];
        int2 t2 = meta[v2 ? jj2 : start];
        int2 t3 = meta[v3 ? jj3 : start];
        uint2 u0 = *(const uint2*)(xb + (unsigned)t0.x + coffb);
        uint2 u1 = *(const uint2*)(xb + (unsigned)t1.x + coffb);
        uint2 u2 = *(const uint2*)(xb + (unsigned)t2.x + coffb);
        uint2 u3 = *(const uint2*)(xb + (unsigned)t3.x + coffb);
        float w0 = v0 ? __int_as_float(t0.y) : 0.f;
        float w1 = v1 ? __int_as_float(t1.y) : 0.f;
        float w2 = v2 ? __int_as_float(t2.y) : 0.f;
        float w3 = v3 ? __int_as_float(t3.y) : 0.f;
        a0 = fmaf(w0, bflo(u0.x), a0);
        a1 = fmaf(w0, bfhi(u0.x), a1);
        a2 = fmaf(w0, bflo(u0.y), a2);
        a3 = fmaf(w0, bfhi(u0.y), a3);
        a0 = fmaf(w1, bflo(u1.x), a0);
        a1 = fmaf(w1, bfhi(u1.x), a1);
        a2 = fmaf(w1, bflo(u1.y), a2);
        a3 = fmaf(w1, bfhi(u1.y), a3);
        a0 = fmaf(w2, bflo(u2.x), a0);
        a1 = fmaf(w2, bfhi(u2.x), a1);
        a2 = fmaf(w2, bflo(u2.y), a2);
        a3 = fmaf(w2, bfhi(u2.y), a3);
        a0 = fmaf(w3, bflo(u3.x), a0);
        a1 = fmaf(w3, bfhi(u3.x), a1);
        a2 = fmaf(w3, bflo(u3.y), a2);
        a3 = fmaf(w3, bfhi(u3.y), a3);
    }
}

// ---------------- pure SPMM for hops 1..HOPS-1 ------------------------------
__global__ __launch_bounds__(256) void spmm_k(
    const int* __restrict__ rowptr,
    const int2* __restrict__ meta,
    const ushort_t* __restrict__ xs, const ushort_t* __restrict__ xt,
    ushort_t* __restrict__ ns, ushort_t* __restrict__ nt)
{
    const int unit = blockIdx.x * 4 + (threadIdx.x >> 6);   // one wave per unit
    const int lane = threadIdx.x & 63;
    const int q  = lane >> 4;
    const int sl = lane & 15;

    const ushort_t* x; ushort_t* nxt;
    int node;
    if (unit < NPAD) {
        node = unit;
        if (node >= N_NODES) return;
        x = xs; nxt = ns;
    } else {
        node = unit - NPAD;
        if (node >= N_NODES) return;
        x = xt; nxt = nt;
    }

    float a0, a1, a2, a3;
    row_gather(rowptr, meta, (const char*)x, unit, q, sl * 8, a0, a1, a2, a3);

    a0 += __shfl_xor(a0, 16, 64);
    a1 += __shfl_xor(a1, 16, 64);
    a2 += __shfl_xor(a2, 16, 64);
    a3 += __shfl_xor(a3, 16, 64);
    a0 += __shfl_xor(a0, 32, 64);
    a1 += __shfl_xor(a1, 32, 64);
    a2 += __shfl_xor(a2, 32, 64);
    a3 += __shfl_xor(a3, 32, 64);

    if (q == 0) {
        *(uint2*)(nxt + ((size_t)node << 6) + sl * 4) =
            make_uint2(pack_bf16(a0, a1), pack_bf16(a2, a3));
    }
}

// ---------------- fused last hop + combine -----------------------------------
// one wave per NODE: computes hop-3 for BOTH directions in registers, then
// out = bn + sum_h ws[h]*hs_h + sum_h wt[h]*ht_h  (hop-3 terms in f32).
__global__ __launch_bounds__(256) void spmm_last(
    const int* __restrict__ rowptr,
    const int2* __restrict__ meta,
    const ushort_t* __restrict__ xs, const ushort_t* __restrict__ xt,   // hop-2
    const ushort_t* __restrict__ s0, const ushort_t* __restrict__ s1,   // hop-0/1
    const ushort_t* __restrict__ t0, const ushort_t* __restrict__ t1,
    const float* __restrict__ wsv, const float* __restrict__ wtv,
    const float* __restrict__ bn,
    float* __restrict__ out)
{
    const int node = blockIdx.x * 4 + (threadIdx.x >> 6);
    const int lane = threadIdx.x & 63;
    const int q  = lane >> 4;
    const int sl = lane & 15;
    if (node >= N_NODES) return;
    const int coffb = sl * 8;

    float a0, a1, a2, a3, b0, b1, b2, b3;
    row_gather(rowptr, meta, (const char*)xs, node, q, coffb, a0, a1, a2, a3);
    row_gather(rowptr, meta, (const char*)xt, NPAD + node, q, coffb, b0, b1, b2, b3);

    a0 += __shfl_xor(a0, 16, 64);  b0 += __shfl_xor(b0, 16, 64);
    a1 += __shfl_xor(a1, 16, 64);  b1 += __shfl_xor(b1, 16, 64);
    a2 += __shfl_xor(a2, 16, 64);  b2 += __shfl_xor(b2, 16, 64);
    a3 += __shfl_xor(a3, 16, 64);  b3 += __shfl_xor(b3, 16, 64);
    a0 += __shfl_xor(a0, 32, 64);  b0 += __shfl_xor(b0, 32, 64);
    a1 += __shfl_xor(a1, 32, 64);  b1 += __shfl_xor(b1, 32, 64);
    a2 += __shfl_xor(a2, 32, 64);  b2 += __shfl_xor(b2, 32, 64);
    a3 += __shfl_xor(a3, 32, 64);  b3 += __shfl_xor(b3, 32, 64);

    if (q == 0) {
        const size_t ho = ((size_t)node << 6) + sl * 4;    // bf16 elem offset
        uint2 us0 = *(const uint2*)(s0 + ho);
        uint2 us1 = *(const uint2*)(s1 + ho);
        uint2 us2 = *(const uint2*)(xs + ho);
        uint2 ut0 = *(const uint2*)(t0 + ho);
        uint2 ut1 = *(const uint2*)(t1 + ho);
        uint2 ut2 = *(const uint2*)(xt + ho);
        float ws0 = wsv[0], ws1 = wsv[1], ws2 = wsv[2], ws3 = wsv[3];
        float wt0 = wtv[0], wt1 = wtv[1], wt2 = wtv[2], wt3 = wtv[3];
        float4 bb = *(const float4*)(bn + sl * 4);

        float o0 = bb.x + ws0 * bflo(us0.x) + ws1 * bflo(us1.x) + ws2 * bflo(us2.x)
                 + ws3 * a0 + wt0 * bflo(ut0.x) + wt1 * bflo(ut1.x) + wt2 * bflo(ut2.x)
                 + wt3 * b0;
        float o1 = bb.y + ws0 * bfhi(us0.x) + ws1 * bfhi(us1.x) + ws2 * bfhi(us2.x)
                 + ws3 * a1 + wt0 * bfhi(ut0.x) + wt1 * bfhi(ut1.x) + wt2 * bfhi(ut2.x)
                 + wt3 * b1;
        float o2 = bb.z + ws0 * bflo(us0.y) + ws1 * bflo(us1.y) + ws2 * bflo(us2.y)
                 + ws3 * a2 + wt0 * bflo(ut0.y) + wt1 * bflo(ut1.y) + wt2 * bflo(ut2.y)
                 + wt3 * b2;
        float o3 = bb.w + ws0 * bfhi(us0.y) + ws1 * bfhi(us1.y) + ws2 * bfhi(us2.y)
                 + ws3 * a3 + wt0 * bfhi(ut0.y) + wt1 * bfhi(ut1.y) + wt2 * bfhi(ut2.y)
                 + wt3 * b3;

        *(float4*)(out + (size_t)node * OUT + sl * 4) = make_float4(o0, o1, o2, o3);
    }
}

extern "C" void kernel_launch(void* const* d_in, const int* in_sizes, int n_in,
                              void* d_out, int out_size, void* d_ws, size_t ws_size,
                              hipStream_t stream) {
    const float* fsrc = (const float*)d_in[0];
    const float* ftgt = (const float*)d_in[1];
    const int*   erow = (const int*)d_in[2];
    const int*   ecol = (const int*)d_in[3];
    const float* ew   = (const float*)d_in[4];
    const float* Wsrc = (const float*)d_in[5];
    const float* bsrc = (const float*)d_in[6];
    const float* Wtgt = (const float*)d_in[7];
    const float* btgt = (const float*)d_in[8];
    const float* ws   = (const float*)d_in[9];
    const float* wt   = (const float*)d_in[10];
    const float* Wn   = (const float*)d_in[11];
    const float* bn   = (const float*)d_in[12];
    float* out = (float*)d_out;

    const size_t buf = (size_t)N_NODES * OUT;   // elements per hop buffer (64-dim)
    char* p = (char*)d_ws;
    ushort_t* hs[3]; ushort_t* ht[3];
    for (int h = 0; h < 3; ++h) {
        hs[h] = (ushort_t*)p; p += buf * 2;
        ht[h] = (ushort_t*)p; p += buf * 2;
    }
    int2* meta     = (int2*)p;  p += (size_t)NBUCK * CAP * 8;   // sparse layout!
    int2* meta_tmp = (int2*)p;  p += (size_t)NBUCK * CAP * 8;
    int* rowptr    = (int*)p;   p += (size_t)NBUCK * RPS * 4 + 64;
    float* Wc      = (float*)p; p += 512 * OUT * 4;
    float* bc      = (float*)p; p += 128 * 4;
    int* bcur      = (int*)p;   p += 256 * 4;

    const int eblocks = (N_EDGES + EPB - 1) / EPB;   // 1563
    const int gblocks = (N_NODES + 63) / 64;         // 1563

    // fold output projection into input weights
    wcomb_k<<<514, 64, 0, stream>>>(Wsrc, Wtgt, bsrc, btgt, Wn, Wc, bc);

    // input GEMMs, both directions in one launch -> bf16 hop-0 buffers
    gemm_in<<<2 * gblocks, 256, 0, stream>>>(fsrc, ftgt, Wc, bc,
                                             hs[0], ht[0], gblocks);

    // CSR build: fixed-capacity buckets (no counting pre-pass)
    init_k<<<1, 256, 0, stream>>>(bcur);
    fill_p1<<<eblocks, 256, 0, stream>>>(erow, ecol, ew, bcur, meta_tmp);
    fill_p2<<<NBUCK, 256, 0, stream>>>(bcur, meta_tmp, meta, rowptr);

    // hops 1..2: both directions per launch
    spmm_k<<<NTOT / 4, 256, 0, stream>>>(rowptr, meta,
                                         hs[0], ht[0], hs[1], ht[1]);
    spmm_k<<<NTOT / 4, 256, 0, stream>>>(rowptr, meta,
                                         hs[1], ht[1], hs[2], ht[2]);

    // hop 3 fused with the weighted combine + bias
    spmm_last<<<NPAD / 4, 256, 0, stream>>>(rowptr, meta,
                                            hs[2], ht[2], hs[0], hs[1],
                                            ht[0], ht[1], ws, wt, bn, out);
}

// Round 14
// 677.939 us; speedup vs baseline: 1.0543x; 1.0172x over previous
//
#include <hip/hip_runtime.h>

#define N_NODES 100000
#define N_EDGES 3200000
#define FEAT 256
#define HID 128
#define OUT 64
#define HOPS 3

#define NPAD 100352                      // 98*1024, >= N_NODES
#define NTOT (2 * NPAD)                  // combined s|t dst-unit space = 200704
#define NBUCK 196                        // NTOT / 1024 buckets (1024 units each)
#define CAP 36864                        // fixed bucket capacity (mean 32768, +22 sigma)
#define RPS 1028                         // rowptr stride per bucket (1024 starts + end slot)
#define EPB 2048                         // edges per block in CSR-build passes

typedef unsigned short ushort_t;

__device__ __forceinline__ float bf2f(ushort_t u) {
    return __uint_as_float(((unsigned)u) << 16);
}
__device__ __forceinline__ float bflo(unsigned u) { return __uint_as_float(u << 16); }
__device__ __forceinline__ float bfhi(unsigned u) { return __uint_as_float(u & 0xffff0000u); }
__device__ __forceinline__ unsigned pack_bf16(float a, float b) {
    unsigned ua = __float_as_uint(a);
    unsigned ub = __float_as_uint(b);
    ua += 0x7fffu + ((ua >> 16) & 1u);
    ub += 0x7fffu + ((ub >> 16) & 1u);
    return (ua >> 16) | (ub & 0xffff0000u);
}

// ---------------- weight fold: Wc = W_{src,tgt} @ Wn_half ; bc = b @ Wn_half
__global__ __launch_bounds__(64) void wcomb_k(
    const float* __restrict__ Wsrc, const float* __restrict__ Wtgt,
    const float* __restrict__ bsrc, const float* __restrict__ btgt,
    const float* __restrict__ Wn,     // [2*HID, OUT]
    float* __restrict__ Wc,           // [512, 64]
    float* __restrict__ bc)           // [128]
{
    const int blk = blockIdx.x;
    const int j = threadIdx.x;
    if (blk < 512) {
        const float* Wsel = (blk < 256) ? Wsrc : Wtgt;
        const int i = blk & 255;
        const int koff = (blk < 256) ? 0 : HID;
        float acc = 0.f;
        for (int k = 0; k < HID; ++k)
            acc = fmaf(Wsel[i * HID + k], Wn[(koff + k) * OUT + j], acc);
        Wc[blk * OUT + j] = acc;
    } else {
        const float* bsel = (blk == 512) ? bsrc : btgt;
        const int koff = (blk == 512) ? 0 : HID;
        float acc = 0.f;
        for (int k = 0; k < HID; ++k)
            acc = fmaf(bsel[k], Wn[(koff + k) * OUT + j], acc);
        bc[(blk - 512) * OUT + j] = acc;
    }
}

// ---------------- input GEMM (both directions in one launch) ----------------
__global__ __launch_bounds__(256) void gemm_in(
    const float* __restrict__ Xs, const float* __restrict__ Xt,   // [N, FEAT]
    const float* __restrict__ Wc,    // [512, 64] folded weights
    const float* __restrict__ bc,    // [128] folded biases
    ushort_t* __restrict__ hs0, ushort_t* __restrict__ ht0,       // [N, OUT] bf16
    int gblocks)
{
    const int dir = (blockIdx.x >= gblocks) ? 1 : 0;
    const int blk = blockIdx.x - dir * gblocks;
    const float* X = dir ? Xt : Xs;
    const float* B = Wc + dir * 256 * OUT;
    const float* bias = bc + dir * OUT;
    ushort_t* h0 = dir ? ht0 : hs0;

    __shared__ __align__(16) float at[64][76];   // A transposed [kk][row]
    __shared__ __align__(16) float bs[64][OUT];  // B chunk [kk][j]
    const int tid = threadIdx.x;
    const int tx = tid & 15;
    const int ty = tid >> 4;
    const int row0 = blk * 64;

    float acc[4][4];
#pragma unroll
    for (int r = 0; r < 4; ++r)
#pragma unroll
        for (int c = 0; c < 4; ++c) acc[r][c] = 0.f;

    for (int chunk = 0; chunk < 4; ++chunk) {
        const int kbase = chunk * 64;
        {
            int lc = tid & 15, lr = tid >> 4;
#pragma unroll
            for (int p = 0; p < 4; ++p) {
                int r = lr + p * 16;
                int grow = row0 + r; if (grow > N_NODES - 1) grow = N_NODES - 1;
                float4 v = *(const float4*)(X + (size_t)grow * FEAT + kbase + lc * 4);
                float vv[4] = {v.x, v.y, v.z, v.w};
#pragma unroll
                for (int i = 0; i < 4; ++i) {
                    int ii = (i + lc) & 3;
                    at[lc * 4 + ii][r] = vv[ii];
                }
            }
        }
        {
            int jf = tid & 15, kk0 = tid >> 4;
#pragma unroll
            for (int p = 0; p < 4; ++p) {
                int kk = kk0 + p * 16;
                *(float4*)&bs[kk][jf * 4] =
                    *(const float4*)(B + (size_t)(kbase + kk) * OUT + jf * 4);
            }
        }
        __syncthreads();
#pragma unroll 8
        for (int kk = 0; kk < 64; ++kk) {
            float4 a = *(const float4*)&at[kk][ty * 4];
            float4 b = *(const float4*)&bs[kk][tx * 4];
            float av[4] = {a.x, a.y, a.z, a.w};
            float bv[4] = {b.x, b.y, b.z, b.w};
#pragma unroll
            for (int r = 0; r < 4; ++r)
#pragma unroll
                for (int c = 0; c < 4; ++c)
                    acc[r][c] = fmaf(av[r], bv[c], acc[r][c]);
        }
        __syncthreads();
    }

    float4 bj = *(const float4*)(bias + tx * 4);
    float bjv[4] = {bj.x, bj.y, bj.z, bj.w};
#pragma unroll
    for (int r = 0; r < 4; ++r) {
        int grow = row0 + ty * 4 + r;
        if (grow < N_NODES) {
            float o[4];
#pragma unroll
            for (int c = 0; c < 4; ++c) o[c] = acc[r][c] + bjv[c];
            size_t off = (size_t)grow * OUT + tx * 4;
            *(uint2*)(h0 + off) = make_uint2(pack_bf16(o[0], o[1]), pack_bf16(o[2], o[3]));
        }
    }
}

// ---------------- init per-bucket allocator cursors -------------------------
__global__ __launch_bounds__(256) void init_k(int* __restrict__ bcur) {
    int t = threadIdx.x;
    if (t < NBUCK) bcur[t] = t * CAP;
}

// ---------------- CSR build pass 1: multisplit scatter into buckets ---------
// entry: .x = src(17b) | dstlow(10b)<<17 ; .y = weight bits
// 4-wave-private histograms/cursors (quarter LDS-atomic collisions);
// int4/float4 vectorized edge loads (N_EDGES % 8 == 0 -> all-or-none/thread).
__global__ __launch_bounds__(256) void fill_p1(
    const int* __restrict__ erow, const int* __restrict__ ecol,
    const float* __restrict__ ew,
    int* __restrict__ bcur, int2* __restrict__ meta_tmp)
{
    __shared__ int2 stage[2 * EPB];          // 32 KB
    __shared__ unsigned char bkt[2 * EPB];   // 4 KB
    __shared__ int hist4[4][256];            // per-wave counts -> cursors
    __shared__ int loff[256], gbase[256];
    __shared__ int sdata[256];
    const int tid = threadIdx.x;
    const int wid = tid >> 6;
    const int base = blockIdx.x * EPB;
    const int n = min(EPB, N_EDGES - base);

    for (int i = tid; i < 1024; i += 256) ((int*)hist4)[i] = 0;
    __syncthreads();

    // 8 consecutive edges per thread, vector loads
    const int e0 = base + tid * 8;
    const bool vld = (e0 < N_EDGES);         // all 8 valid or none
    int r[8], c[8], wb[8];
    if (vld) {
        int4 ra = *(const int4*)(erow + e0);
        int4 rb = *(const int4*)(erow + e0 + 4);
        int4 ca = *(const int4*)(ecol + e0);
        int4 cb = *(const int4*)(ecol + e0 + 4);
        float4 wa = *(const float4*)(ew + e0);
        float4 wz = *(const float4*)(ew + e0 + 4);
        r[0]=ra.x; r[1]=ra.y; r[2]=ra.z; r[3]=ra.w;
        r[4]=rb.x; r[5]=rb.y; r[6]=rb.z; r[7]=rb.w;
        c[0]=ca.x; c[1]=ca.y; c[2]=ca.z; c[3]=ca.w;
        c[4]=cb.x; c[5]=cb.y; c[6]=cb.z; c[7]=cb.w;
        wb[0]=__float_as_int(wa.x); wb[1]=__float_as_int(wa.y);
        wb[2]=__float_as_int(wa.z); wb[3]=__float_as_int(wa.w);
        wb[4]=__float_as_int(wz.x); wb[5]=__float_as_int(wz.y);
        wb[6]=__float_as_int(wz.z); wb[7]=__float_as_int(wz.w);
#pragma unroll
        for (int k = 0; k < 8; ++k) {
            atomicAdd(&hist4[wid][r[k] >> 10], 1);
            atomicAdd(&hist4[wid][(NPAD + c[k]) >> 10], 1);
        }
    }
    __syncthreads();

    // per-bin totals + block-local scan + per-wave cursor bases
    int c0 = hist4[0][tid], c1 = hist4[1][tid], c2 = hist4[2][tid], c3 = hist4[3][tid];
    int lc = c0 + c1 + c2 + c3;
    sdata[tid] = lc;
    __syncthreads();
    for (int off = 1; off < 256; off <<= 1) {
        int t = (tid >= off) ? sdata[tid - off] : 0;
        __syncthreads();
        sdata[tid] += t;
        __syncthreads();
    }
    int excl = sdata[tid] - lc;
    loff[tid] = excl;
    hist4[0][tid] = excl;                    // wave-private cursors (disjoint)
    hist4[1][tid] = excl + c0;
    hist4[2][tid] = excl + c0 + c1;
    hist4[3][tid] = excl + c0 + c1 + c2;
    gbase[tid] = (lc > 0) ? atomicAdd(&bcur[tid], lc) : 0;
    __syncthreads();

    if (vld) {
#pragma unroll
        for (int k = 0; k < 8; ++k) {
            int bs_ = r[k] >> 10;
            int l = atomicAdd(&hist4[wid][bs_], 1);
            stage[l] = make_int2(c[k] | ((r[k] & 1023) << 17), wb[k]);
            bkt[l] = (unsigned char)bs_;
            int ut = NPAD + c[k];
            int bt_ = ut >> 10;
            int l2 = atomicAdd(&hist4[wid][bt_], 1);
            stage[l2] = make_int2(r[k] | ((ut & 1023) << 17), wb[k]);
            bkt[l2] = (unsigned char)bt_;
        }
    }
    __syncthreads();
    const int tot = 2 * n;
    for (int i = tid; i < tot; i += 256) {
        int b = bkt[i];
        meta_tmp[(size_t)gbase[b] + (i - loff[b])] = stage[i];
    }
}

// ---------------- CSR build pass 2: within-bucket sort + rowptr -------------
// final meta entry: .x = src row BYTE offset (src*128), .y = weight bits
__global__ __launch_bounds__(256) void fill_p2(
    const int* __restrict__ bcur,
    const int2* __restrict__ meta_tmp,
    int2* __restrict__ meta, int* __restrict__ rowptr)
{
    __shared__ int cnt[1024];
    __shared__ int sdata[256];
    const int tid = threadIdx.x;
    const int b = blockIdx.x;
    const int seg0 = b * CAP;
    const int seg1 = bcur[b];

    for (int i = tid; i < 1024; i += 256) cnt[i] = 0;
    __syncthreads();
    for (int j = seg0 + tid; j < seg1; j += 256) {
        int2 e = meta_tmp[j];
        atomicAdd(&cnt[(e.x >> 17) & 1023], 1);
    }
    __syncthreads();
    int4 v = *(int4*)&cnt[tid * 4];
    int tsum = v.x + v.y + v.z + v.w;
    sdata[tid] = tsum;
    __syncthreads();
    for (int off = 1; off < 256; off <<= 1) {
        int t = (tid >= off) ? sdata[tid - off] : 0;
        __syncthreads();
        sdata[tid] += t;
        __syncthreads();
    }
    int excl = sdata[tid] - tsum;
    int4 o;
    o.x = seg0 + excl;
    o.y = o.x + v.x;
    o.z = o.y + v.y;
    o.w = o.z + v.z;
    *(int4*)(rowptr + b * RPS + tid * 4) = o;    // row starts (absolute into meta)
    *(int4*)&cnt[tid * 4] = o;                   // cursors
    if (tid == 0) rowptr[b * RPS + 1024] = seg1; // bucket end slot
    __syncthreads();
    for (int j = seg0 + tid; j < seg1; j += 256) {
        int2 e = meta_tmp[j];
        int pos = atomicAdd(&cnt[(e.x >> 17) & 1023], 1);
        meta[pos] = make_int2((e.x & 0x1ffff) << 7, e.y);   // byte offset of src row
    }
}

// ---------------- shared row-gather core (quarter-wave, 16-edge iters) ------
__device__ __forceinline__ void row_gather(
    const int* __restrict__ rowptr, const int2* __restrict__ meta,
    const char* __restrict__ xb, int unit, int q, int coffb,
    float& a0, float& a1, float& a2, float& a3)
{
    const int rbase = (unit >> 10) * RPS + (unit & 1023);
    const int start = rowptr[rbase];
    const int end   = rowptr[rbase + 1];

    a0 = 0.f; a1 = 0.f; a2 = 0.f; a3 = 0.f;

    int jb = start;
    int2 m0, m1, m2, m3;
    bool have = (jb + 15 < end);
    if (have) {
        m0 = meta[jb + q];
        m1 = meta[jb + 4 + q];
        m2 = meta[jb + 8 + q];
        m3 = meta[jb + 12 + q];
    }
    while (have) {
        uint2 u0 = *(const uint2*)(xb + (unsigned)m0.x + coffb);
        uint2 u1 = *(const uint2*)(xb + (unsigned)m1.x + coffb);
        uint2 u2 = *(const uint2*)(xb + (unsigned)m2.x + coffb);
        uint2 u3 = *(const uint2*)(xb + (unsigned)m3.x + coffb);
        float w0 = __int_as_float(m0.y), w1 = __int_as_float(m1.y);
        float w2 = __int_as_float(m2.y), w3 = __int_as_float(m3.y);

        const int jn = jb + 16;
        have = (jn + 15 < end);
        if (have) {
            m0 = meta[jn + q];
            m1 = meta[jn + 4 + q];
            m2 = meta[jn + 8 + q];
            m3 = meta[jn + 12 + q];
        }
        jb = jn;

        a0 = fmaf(w0, bflo(u0.x), a0);
        a1 = fmaf(w0, bfhi(u0.x), a1);
        a2 = fmaf(w0, bflo(u0.y), a2);
        a3 = fmaf(w0, bfhi(u0.y), a3);
        a0 = fmaf(w1, bflo(u1.x), a0);
        a1 = fmaf(w1, bfhi(u1.x), a1);
        a2 = fmaf(w1, bflo(u1.y), a2);
        a3 = fmaf(w1, bfhi(u1.y), a3);
        a0 = fmaf(w2, bflo(u2.x), a0);
        a1 = fmaf(w2, bfhi(u2.x), a1);
        a2 = fmaf(w2, bflo(u2.y), a2);
        a3 = fmaf(w2, bfhi(u2.y), a3);
        a0 = fmaf(w3, bflo(u3.x), a0);
        a1 = fmaf(w3, bfhi(u3.x), a1);
        a2 = fmaf(w3, bflo(u3.y), a2);
        a3 = fmaf(w3, bfhi(u3.y), a3);
    }

    if (jb < end) {                      // single masked 16-slot tail
        int jj0 = jb + q,      jj1 = jb + 4 + q;
        int jj2 = jb + 8 + q,  jj3 = jb + 12 + q;
        bool v0 = jj0 < end, v1 = jj1 < end, v2 = jj2 < end, v3 = jj3 < end;
        int2 t0 = meta[v0 ? jj0 : start];
        int2 t1 = meta[v1 ? jj1 : start];
        int2 t2 = meta[v2 ? jj2 : start];
        int2 t3 = meta[v3 ? jj3 : start];
        uint2 u0 = *(const uint2*)(xb + (unsigned)t0.x + coffb);
        uint2 u1 = *(const uint2*)(xb + (unsigned)t1.x + coffb);
        uint2 u2 = *(const uint2*)(xb + (unsigned)t2.x + coffb);
        uint2 u3 = *(const uint2*)(xb + (unsigned)t3.x + coffb);
        float w0 = v0 ? __int_as_float(t0.y) : 0.f;
        float w1 = v1 ? __int_as_float(t1.y) : 0.f;
        float w2 = v2 ? __int_as_float(t2.y) : 0.f;
        float w3 = v3 ? __int_as_float(t3.y) : 0.f;
        a0 = fmaf(w0, bflo(u0.x), a0);
        a1 = fmaf(w0, bfhi(u0.x), a1);
        a2 = fmaf(w0, bflo(u0.y), a2);
        a3 = fmaf(w0, bfhi(u0.y), a3);
        a0 = fmaf(w1, bflo(u1.x), a0);
        a1 = fmaf(w1, bfhi(u1.x), a1);
        a2 = fmaf(w1, bflo(u1.y), a2);
        a3 = fmaf(w1, bfhi(u1.y), a3);
        a0 = fmaf(w2, bflo(u2.x), a0);
        a1 = fmaf(w2, bfhi(u2.x), a1);
        a2 = fmaf(w2, bflo(u2.y), a2);
        a3 = fmaf(w2, bfhi(u2.y), a3);
        a0 = fmaf(w3, bflo(u3.x), a0);
        a1 = fmaf(w3, bfhi(u3.x), a1);
        a2 = fmaf(w3, bflo(u3.y), a2);
        a3 = fmaf(w3, bfhi(u3.y), a3);
    }
}

// ---------------- pure SPMM for hops 1..HOPS-1 ------------------------------
__global__ __launch_bounds__(256) void spmm_k(
    const int* __restrict__ rowptr,
    const int2* __restrict__ meta,
    const ushort_t* __restrict__ xs, const ushort_t* __restrict__ xt,
    ushort_t* __restrict__ ns, ushort_t* __restrict__ nt)
{
    const int unit = blockIdx.x * 4 + (threadIdx.x >> 6);   // one wave per unit
    const int lane = threadIdx.x & 63;
    const int q  = lane >> 4;
    const int sl = lane & 15;

    const ushort_t* x; ushort_t* nxt;
    int node;
    if (unit < NPAD) {
        node = unit;
        if (node >= N_NODES) return;
        x = xs; nxt = ns;
    } else {
        node = unit - NPAD;
        if (node >= N_NODES) return;
        x = xt; nxt = nt;
    }

    float a0, a1, a2, a3;
    row_gather(rowptr, meta, (const char*)x, unit, q, sl * 8, a0, a1, a2, a3);

    a0 += __shfl_xor(a0, 16, 64);
    a1 += __shfl_xor(a1, 16, 64);
    a2 += __shfl_xor(a2, 16, 64);
    a3 += __shfl_xor(a3, 16, 64);
    a0 += __shfl_xor(a0, 32, 64);
    a1 += __shfl_xor(a1, 32, 64);
    a2 += __shfl_xor(a2, 32, 64);
    a3 += __shfl_xor(a3, 32, 64);

    if (q == 0) {
        *(uint2*)(nxt + ((size_t)node << 6) + sl * 4) =
            make_uint2(pack_bf16(a0, a1), pack_bf16(a2, a3));
    }
}

// ---------------- fused last hop + combine -----------------------------------
__global__ __launch_bounds__(256) void spmm_last(
    const int* __restrict__ rowptr,
    const int2* __restrict__ meta,
    const ushort_t* __restrict__ xs, const ushort_t* __restrict__ xt,   // hop-2
    const ushort_t* __restrict__ s0, const ushort_t* __restrict__ s1,   // hop-0/1
    const ushort_t* __restrict__ t0, const ushort_t* __restrict__ t1,
    const float* __restrict__ wsv, const float* __restrict__ wtv,
    const float* __restrict__ bn,
    float* __restrict__ out)
{
    const int node = blockIdx.x * 4 + (threadIdx.x >> 6);
    const int lane = threadIdx.x & 63;
    const int q  = lane >> 4;
    const int sl = lane & 15;
    if (node >= N_NODES) return;
    const int coffb = sl * 8;

    float a0, a1, a2, a3, b0, b1, b2, b3;
    row_gather(rowptr, meta, (const char*)xs, node, q, coffb, a0, a1, a2, a3);
    row_gather(rowptr, meta, (const char*)xt, NPAD + node, q, coffb, b0, b1, b2, b3);

    a0 += __shfl_xor(a0, 16, 64);  b0 += __shfl_xor(b0, 16, 64);
    a1 += __shfl_xor(a1, 16, 64);  b1 += __shfl_xor(b1, 16, 64);
    a2 += __shfl_xor(a2, 16, 64);  b2 += __shfl_xor(b2, 16, 64);
    a3 += __shfl_xor(a3, 16, 64);  b3 += __shfl_xor(b3, 16, 64);
    a0 += __shfl_xor(a0, 32, 64);  b0 += __shfl_xor(b0, 32, 64);
    a1 += __shfl_xor(a1, 32, 64);  b1 += __shfl_xor(b1, 32, 64);
    a2 += __shfl_xor(a2, 32, 64);  b2 += __shfl_xor(b2, 32, 64);
    a3 += __shfl_xor(a3, 32, 64);  b3 += __shfl_xor(b3, 32, 64);

    if (q == 0) {
        const size_t ho = ((size_t)node << 6) + sl * 4;    // bf16 elem offset
        uint2 us0 = *(const uint2*)(s0 + ho);
        uint2 us1 = *(const uint2*)(s1 + ho);
        uint2 us2 = *(const uint2*)(xs + ho);
        uint2 ut0 = *(const uint2*)(t0 + ho);
        uint2 ut1 = *(const uint2*)(t1 + ho);
        uint2 ut2 = *(const uint2*)(xt + ho);
        float ws0 = wsv[0], ws1 = wsv[1], ws2 = wsv[2], ws3 = wsv[3];
        float wt0 = wtv[0], wt1 = wtv[1], wt2 = wtv[2], wt3 = wtv[3];
        float4 bb = *(const float4*)(bn + sl * 4);

        float o0 = bb.x + ws0 * bflo(us0.x) + ws1 * bflo(us1.x) + ws2 * bflo(us2.x)
                 + ws3 * a0 + wt0 * bflo(ut0.x) + wt1 * bflo(ut1.x) + wt2 * bflo(ut2.x)
                 + wt3 * b0;
        float o1 = bb.y + ws0 * bfhi(us0.x) + ws1 * bfhi(us1.x) + ws2 * bfhi(us2.x)
                 + ws3 * a1 + wt0 * bfhi(ut0.x) + wt1 * bfhi(ut1.x) + wt2 * bfhi(ut2.x)
                 + wt3 * b1;
        float o2 = bb.z + ws0 * bflo(us0.y) + ws1 * bflo(us1.y) + ws2 * bflo(us2.y)
                 + ws3 * a2 + wt0 * bflo(ut0.y) + wt1 * bflo(ut1.y) + wt2 * bflo(ut2.y)
                 + wt3 * b2;
        float o3 = bb.w + ws0 * bfhi(us0.y) + ws1 * bfhi(us1.y) + ws2 * bfhi(us2.y)
                 + ws3 * a3 + wt0 * bfhi(ut0.y) + wt1 * bfhi(ut1.y) + wt2 * bfhi(ut2.y)
                 + wt3 * b3;

        *(float4*)(out + (size_t)node * OUT + sl * 4) = make_float4(o0, o1, o2, o3);
    }
}

extern "C" void kernel_launch(void* const* d_in, const int* in_sizes, int n_in,
                              void* d_out, int out_size, void* d_ws, size_t ws_size,
                              hipStream_t stream) {
    const float* fsrc = (const float*)d_in[0];
    const float* ftgt = (const float*)d_in[1];
    const int*   erow = (const int*)d_in[2];
    const int*   ecol = (const int*)d_in[3];
    const float* ew   = (const float*)d_in[4];
    const float* Wsrc = (const float*)d_in[5];
    const float* bsrc = (const float*)d_in[6];
    const float* Wtgt = (const float*)d_in[7];
    const float* btgt = (const float*)d_in[8];
    const float* ws   = (const float*)d_in[9];
    const float* wt   = (const float*)d_in[10];
    const float* Wn   = (const float*)d_in[11];
    const float* bn   = (const float*)d_in[12];
    float* out = (float*)d_out;

    const size_t buf = (size_t)N_NODES * OUT;   // elements per hop buffer (64-dim)
    char* p = (char*)d_ws;
    ushort_t* hs[3]; ushort_t* ht[3];
    for (int h = 0; h < 3; ++h) {
        hs[h] = (ushort_t*)p; p += buf * 2;
        ht[h] = (ushort_t*)p; p += buf * 2;
    }
    int2* meta     = (int2*)p;  p += (size_t)NBUCK * CAP * 8;   // sparse layout!
    int2* meta_tmp = (int2*)p;  p += (size_t)NBUCK * CAP * 8;
    int* rowptr    = (int*)p;   p += (size_t)NBUCK * RPS * 4 + 64;
    float* Wc      = (float*)p; p += 512 * OUT * 4;
    float* bc      = (float*)p; p += 128 * 4;
    int* bcur      = (int*)p;   p += 256 * 4;

    const int eblocks = (N_EDGES + EPB - 1) / EPB;   // 1563
    const int gblocks = (N_NODES + 63) / 64;         // 1563

    // fold output projection into input weights
    wcomb_k<<<514, 64, 0, stream>>>(Wsrc, Wtgt, bsrc, btgt, Wn, Wc, bc);

    // input GEMMs, both directions in one launch -> bf16 hop-0 buffers
    gemm_in<<<2 * gblocks, 256, 0, stream>>>(fsrc, ftgt, Wc, bc,
                                             hs[0], ht[0], gblocks);

    // CSR build: fixed-capacity buckets (no counting pre-pass)
    init_k<<<1, 256, 0, stream>>>(bcur);
    fill_p1<<<eblocks, 256, 0, stream>>>(erow, ecol, ew, bcur, meta_tmp);
    fill_p2<<<NBUCK, 256, 0, stream>>>(bcur, meta_tmp, meta, rowptr);

    // hops 1..2: both directions per launch
    spmm_k<<<NTOT / 4, 256, 0, stream>>>(rowptr, meta,
                                         hs[0], ht[0], hs[1], ht[1]);
    spmm_k<<<NTOT / 4, 256, 0, stream>>>(rowptr, meta,
                                         hs[1], ht[1], hs[2], ht[2]);

    // hop 3 fused with the weighted combine + bias
    spmm_last<<<NPAD / 4, 256, 0, stream>>>(rowptr, meta,
                                            hs[2], ht[2], hs[0], hs[1],
                                            ht[0], ht[1], ws, wt, bn, out);
}